// Round 5
// baseline (226.640 us; speedup 1.0000x reference)
//
#include <hip/hip_runtime.h>
#include <hip/hip_fp16.h>
#include <stdint.h>

#define N_EDGES 200000
#define N_NODES 50000
#define BM 32
#define NT 64

typedef _Float16 f16x8 __attribute__((ext_vector_type(8)));
typedef float f32x4 __attribute__((ext_vector_type(4)));

// ---- prep_w: W -> f16, scales folded. wt[T*2048 + w*32 + kk] = f16(scale*W[k=T*32+kk][w])
__global__ void prep_w(const float* __restrict__ W0, const float* __restrict__ W1,
                       const float* __restrict__ W2, uint16_t* __restrict__ wt) {
  int o = blockIdx.x * 256 + threadIdx.x;     // 147456 total
  int T = o >> 11, r = o & 2047, w = r >> 5, kk = r & 31;
  int k = T * 32 + kk;
  const float AS = 1.0f / 48.0f;                  // 1/sqrt(2304)
  const float AV = AS * 0.57735026918962576f;     // /sqrt(3)
  const float AT = AS * 0.44721359549995794f;     // /sqrt(5)
  float val;
  if (k < 1024)      val = AS * W0[(k >> 5) * 2048 + (k & 31) * 64 + w];
  else if (k < 2048) { int k2 = k - 1024; val = AV * W1[(k2 >> 5) * 2048 + (k2 & 31) * 64 + w]; }
  else               { int k2 = k - 2048; val = AT * W2[(k2 >> 4) * 1024 + (k2 & 15) * 64 + w]; }
  __half h = __float2half(val);
  wt[o] = *reinterpret_cast<uint16_t*>(&h);
}

// ---- prep_tables: node_tensors -> TA (u-major, 296 u16/row) + TB (m-major, 216 u16/row)
__global__ void prep_tables(const float* __restrict__ nt,
                            uint16_t* __restrict__ ta, uint16_t* __restrict__ tb) {
  long long o = (long long)blockIdx.x * 256 + threadIdx.x;
  if (o >= (long long)N_NODES * 296) return;
  int node = (int)(o / 296);
  int r = (int)(o - (long long)node * 296);
  const float* x = nt + (size_t)node * 208;
  float va = 0.f;
  if (r < 32) va = x[r];
  else if (r < 160) { int q = r - 32;  int u = q >> 2, m = q & 3;  if (m < 3) va = x[32 + u * 3 + m]; }
  else if (r < 288) { int q = r - 160; int u = q >> 3, m = q & 7;  if (m < 5) va = x[128 + u * 5 + m]; }
  __half ha = __float2half(va);
  ta[(size_t)node * 296 + r] = *reinterpret_cast<uint16_t*>(&ha);
  if (r < 216) {
    float vb = 0.f;
    if (r < 32) vb = x[r];
    else if (r < 128) { int q = r - 32;  int m = q >> 5, v = q & 31; vb = x[32 + v * 3 + m]; }
    else if (r < 208) { int q = r - 128; int m = q >> 4, v = q & 15; vb = x[128 + v * 5 + m]; }
    __half hb = __float2half(vb);
    tb[(size_t)node * 216 + r] = *reinterpret_cast<uint16_t*>(&hb);
  }
}

// broadcast one half (sel=0 low, sel=1 high) of a u32 to both halves of a __half2
__device__ __forceinline__ __half2 bcast_half(uint32_t w, int sel) {
  uint32_t hv = sel ? (w >> 16) : (w & 0xffffu);
  hv |= hv << 16;
  union { uint32_t u; __half2 h; } cv; cv.u = hv;
  return cv.h;
}

// W ring load: 4 x dwordx4 per lane from tile Tc. WRA is a uint4[4] array name.
#define LOADW(WRA, TEXPR)                                                       \
  { int Tc_ = (TEXPR);                                                          \
    _Pragma("unroll") for (int nf = 0; nf < 4; ++nf)                            \
      WRA[nf] = wtg4[Tc_ * 256 + nf * 64 + lo4]; }

#define MSTEPA(WRA, A)                                                          \
  _Pragma("unroll") for (int mf = 0; mf < 2; ++mf)                              \
  _Pragma("unroll") for (int nf = 0; nf < 4; ++nf)                              \
    acc[mf][nf] = __builtin_amdgcn_mfma_f32_16x16x32_f16(                       \
        (A)[mf], *(const f16x8*)&WRA[nf], acc[mf][nf], 0, 0, 0);

// S build from registers: element T_ of this lane's row-slice sS (u16[32]).
#define BUILD_SR(T_, A)                                                         \
  _Pragma("unroll") for (int mf = 0; mf < 2; ++mf) {                            \
    __half2 s1b2 = bcast_half(sS[mf][(T_) >> 1], (T_) & 1);                     \
    union { uint32_t u[4]; f16x8 v; } au_;                                      \
    _Pragma("unroll") for (int q = 0; q < 4; ++q) {                             \
      __half2 p = __hmul2(s1b2, ((const __half2*)&s2pk[mf])[q]);                \
      au_.u[q] = *(uint32_t*)&p;                                                \
    }                                                                           \
    (A)[mf] = au_.v;                                                            \
  }

// V build from registers: UL in 0..7 within current 8-u group (vS = 64B slice).
#define BUILD_VR(UL, A)                                                         \
  _Pragma("unroll") for (int mf = 0; mf < 2; ++mf) {                            \
    __half2 va0 = bcast_half(vS[mf][(UL) * 2], 0);                              \
    __half2 va1 = bcast_half(vS[mf][(UL) * 2], 1);                              \
    __half2 va2 = bcast_half(vS[mf][(UL) * 2 + 1], 0);                          \
    union { uint32_t u[4]; f16x8 v; } au_;                                      \
    _Pragma("unroll") for (int q = 0; q < 4; ++q) {                             \
      __half2 p = __hmul2(va0, ((const __half2*)&v2pk[mf][0])[q]);              \
      p = __hfma2(va1, ((const __half2*)&v2pk[mf][1])[q], p);                   \
      p = __hfma2(va2, ((const __half2*)&v2pk[mf][2])[q], p);                   \
      au_.u[q] = *(uint32_t*)&p;                                                \
    }                                                                           \
    (A)[mf] = au_.v;                                                            \
  }

// T build from registers: TT_ in 0..3 within current half (tS = 4 uint4/row slice,
// already selected for this lane's gh = g>>1).
#define BUILD_TR(TT_, A)                                                        \
  _Pragma("unroll") for (int mm = 0; mm < 2; ++mm) {                            \
    __half2 tb0 = bcast_half(tS[mm][(TT_) * 4 + 0], 0);                         \
    __half2 tb1 = bcast_half(tS[mm][(TT_) * 4 + 0], 1);                         \
    __half2 tb2 = bcast_half(tS[mm][(TT_) * 4 + 1], 0);                         \
    __half2 tb3 = bcast_half(tS[mm][(TT_) * 4 + 1], 1);                         \
    __half2 tb4 = bcast_half(tS[mm][(TT_) * 4 + 2], 0);                         \
    union { uint32_t u[4]; f16x8 v; } au_;                                      \
    _Pragma("unroll") for (int q = 0; q < 4; ++q) {                             \
      __half2 p = __hmul2(tb0, ((const __half2*)&t2pk[mm][0])[q]);              \
      p = __hfma2(tb1, ((const __half2*)&t2pk[mm][1])[q], p);                   \
      p = __hfma2(tb2, ((const __half2*)&t2pk[mm][2])[q], p);                   \
      p = __hfma2(tb3, ((const __half2*)&t2pk[mm][3])[q], p);                   \
      p = __hfma2(tb4, ((const __half2*)&t2pk[mm][4])[q], p);                   \
      au_.u[q] = *(uint32_t*)&p;                                                \
    }                                                                           \
    (A)[mm] = au_.v;                                                            \
  }

#define RING_SR(WRA, T_)     { f16x8 a[2]; BUILD_SR(T_, a); MSTEPA(WRA, a); LOADW(WRA, (T_) + 4); }
#define RING_VR(WRA, UL, TB) { f16x8 a[2]; BUILD_VR(UL, a); MSTEPA(WRA, a); LOADW(WRA, (TB) + (UL) + 4); }
#define WRAPT(X) ((X) <= 71 ? (X) : (X) - 8)
#define RING_TR(WRA, TT_, TB){ f16x8 a[2]; BUILD_TR(TT_, a); MSTEPA(WRA, a); LOADW(WRA, WRAPT((TB) + (TT_) + 4)); }

// Register-staged x1: NO x1 LDS staging, no gather->LDS drain, no ds_read in the
// K-loop. Each lane loads its own rows' (c, 16+c) per-phase slices directly from
// global (L1/L2-cached; 4-lane redundancy across g accepted). LDS holds only the
// 32x68 f32 epilogue tile (8704 B) -> occupancy is VGPR-bound, not LDS-bound.
// All register-slice indices are compile-time (loops fully unrolled) to avoid the
// runtime-indexed-register->scratch trap (R1/R3 spills were the other trap:
// multi-arg __launch_bounds__; single-arg only here).
__global__ __launch_bounds__(NT) void edge_main(
    const uint16_t* __restrict__ ta, const uint16_t* __restrict__ tbl,
    const int* __restrict__ ei, const uint16_t* __restrict__ wt,
    const float* __restrict__ A1, const float* __restrict__ b1,
    const float* __restrict__ A2, const float* __restrict__ b2,
    float* __restrict__ out)
{
  __shared__ alignas(16) float etile[32 * 68];   // 8704 B
  const int tid = threadIdx.x;
  const int e0 = blockIdx.x * BM;   // 200000 = 6250*32, no tail
  const int lane = tid, c = lane & 15, g = lane >> 4;
  const int lo4 = c * 4 + g;

  const unsigned char* x1p[2];
  const unsigned char* tbp[2];
  #pragma unroll
  for (int mf = 0; mf < 2; ++mf) {
    int e = e0 + mf * 16 + c;
    int src = ei[e];
    int dst = ei[N_EDGES + e];
    x1p[mf] = (const unsigned char*)ta + (size_t)src * 592;
    tbp[mf] = (const unsigned char*)tbl + (size_t)dst * 432;
  }

  f32x4 acc[2][4];
  #pragma unroll
  for (int mf = 0; mf < 2; ++mf)
    #pragma unroll
    for (int nf = 0; nf < 4; ++nf) acc[mf][nf] = (f32x4){0.f, 0.f, 0.f, 0.f};

  const uint4* wtg4 = (const uint4*)wt;
  uint4 wr0[4], wr1[4], wr2[4], wr3[4];   // 4-deep W ring, literal-indexed
  LOADW(wr0, 0); LOADW(wr1, 1); LOADW(wr2, 2); LOADW(wr3, 3);

  // ---- S phase: tiles 0..31 ----
  {
    uint4 s2pk[2];
    #pragma unroll
    for (int mf = 0; mf < 2; ++mf) s2pk[mf] = *(const uint4*)(tbp[mf] + g * 16);
    uint32_t sS[2][16];
    #pragma unroll
    for (int mf = 0; mf < 2; ++mf)
      #pragma unroll
      for (int i = 0; i < 4; ++i) {
        uint4 q_ = *(const uint4*)(x1p[mf] + i * 16);
        sS[mf][i * 4 + 0] = q_.x; sS[mf][i * 4 + 1] = q_.y;
        sS[mf][i * 4 + 2] = q_.z; sS[mf][i * 4 + 3] = q_.w;
      }
    #pragma unroll
    for (int T4 = 0; T4 < 8; ++T4) {
      RING_SR(wr0, T4 * 4 + 0); RING_SR(wr1, T4 * 4 + 1);
      RING_SR(wr2, T4 * 4 + 2); RING_SR(wr3, T4 * 4 + 3);
    }
  }

  // ---- V phase: tiles 32..63, four 8-u groups, 64 B/row slice each ----
  {
    uint4 v2pk[2][3];
    #pragma unroll
    for (int mf = 0; mf < 2; ++mf)
      #pragma unroll
      for (int m3 = 0; m3 < 3; ++m3)
        v2pk[mf][m3] = *(const uint4*)(tbp[mf] + 64 + m3 * 64 + g * 16);
    for (int G = 0; G < 4; ++G) {
      uint32_t vS[2][16];
      #pragma unroll
      for (int mf = 0; mf < 2; ++mf)
        #pragma unroll
        for (int i = 0; i < 4; ++i) {
          uint4 q_ = *(const uint4*)(x1p[mf] + 64 + G * 64 + i * 16);
          vS[mf][i * 4 + 0] = q_.x; vS[mf][i * 4 + 1] = q_.y;
          vS[mf][i * 4 + 2] = q_.z; vS[mf][i * 4 + 3] = q_.w;
        }
      const int Tb = 32 + G * 8;
      RING_VR(wr0, 0, Tb); RING_VR(wr1, 1, Tb); RING_VR(wr2, 2, Tb); RING_VR(wr3, 3, Tb);
      RING_VR(wr0, 4, Tb); RING_VR(wr1, 5, Tb); RING_VR(wr2, 6, Tb); RING_VR(wr3, 7, Tb);
    }
  }

  // ---- T phase: tiles 64..71, two halves, gh-selected 64 B/row slice each ----
  {
    uint4 t2pk[2][5];
    #pragma unroll
    for (int mm = 0; mm < 2; ++mm)
      #pragma unroll
      for (int m5 = 0; m5 < 5; ++m5)
        t2pk[mm][m5] = *(const uint4*)(tbp[mm] + 256 + m5 * 32 + (g & 1) * 16);
    const int gh16 = (g >> 1) * 16;
    #pragma unroll
    for (int H = 0; H < 2; ++H) {
      uint32_t tS[2][16];
      #pragma unroll
      for (int mm = 0; mm < 2; ++mm)
        #pragma unroll
        for (int i = 0; i < 4; ++i) {
          uint4 q_ = *(const uint4*)(x1p[mm] + 320 + gh16 + H * 128 + i * 32);
          tS[mm][i * 4 + 0] = q_.x; tS[mm][i * 4 + 1] = q_.y;
          tS[mm][i * 4 + 2] = q_.z; tS[mm][i * 4 + 3] = q_.w;
        }
      const int Tb = 64 + H * 4;
      RING_TR(wr0, 0, Tb); RING_TR(wr1, 1, Tb); RING_TR(wr2, 2, Tb); RING_TR(wr3, 3, Tb);
    }
  }

  // ---- epilogue: e-tile to LDS, then MLP head ----
  #pragma unroll
  for (int mf = 0; mf < 2; ++mf)
    #pragma unroll
    for (int nf = 0; nf < 4; ++nf)
      #pragma unroll
      for (int rr = 0; rr < 4; ++rr)
        etile[(mf * 16 + g * 4 + rr) * 68 + nf * 16 + c] = acc[mf][nf][rr];
  __syncthreads();

  // ---- MLP head: 2 lanes/edge (j-halves of 16), 64 lanes = 32 edges ----
  {
    int el = lane >> 1, jh = lane & 1;
    const float* er = etile + (size_t)el * 68;
    float hacc[16];
    #pragma unroll
    for (int j = 0; j < 16; ++j) hacc[j] = b1[jh * 16 + j];
    for (int w4 = 0; w4 < 16; ++w4) {
      float4 ea = *(const float4*)(er + w4 * 4);
      #pragma unroll
      for (int q2 = 0; q2 < 4; ++q2) {
        float ev = (&ea.x)[q2];
        int w = w4 * 4 + q2;
        float4 a0 = *(const float4*)(A1 + w * 32 + jh * 16);
        float4 a1 = *(const float4*)(A1 + w * 32 + jh * 16 + 4);
        float4 a2 = *(const float4*)(A1 + w * 32 + jh * 16 + 8);
        float4 a3 = *(const float4*)(A1 + w * 32 + jh * 16 + 12);
        hacc[0]  += ev * a0.x; hacc[1]  += ev * a0.y; hacc[2]  += ev * a0.z; hacc[3]  += ev * a0.w;
        hacc[4]  += ev * a1.x; hacc[5]  += ev * a1.y; hacc[6]  += ev * a1.z; hacc[7]  += ev * a1.w;
        hacc[8]  += ev * a2.x; hacc[9]  += ev * a2.y; hacc[10] += ev * a2.z; hacc[11] += ev * a2.w;
        hacc[12] += ev * a3.x; hacc[13] += ev * a3.y; hacc[14] += ev * a3.z; hacc[15] += ev * a3.w;
      }
    }
    float o = 0.f;
    #pragma unroll
    for (int j = 0; j < 16; ++j) {
      float z = hacc[j];
      o += (z / (1.f + __expf(-z))) * A2[jh * 16 + j];
    }
    o += __shfl_xor(o, 1);
    int e = e0 + el;
    if (jh == 0 && e < N_EDGES) out[e] = o + b2[0];
  }
}

extern "C" void kernel_launch(void* const* d_in, const int* in_sizes, int n_in,
                              void* d_out, int out_size, void* d_ws, size_t ws_size,
                              hipStream_t stream) {
  const float* nt = (const float*)d_in[0];
  const int*   ei = (const int*)d_in[1];
  const float* W0 = (const float*)d_in[2];
  const float* W1 = (const float*)d_in[3];
  const float* W2 = (const float*)d_in[4];
  const float* A1 = (const float*)d_in[5];
  const float* b1 = (const float*)d_in[6];
  const float* A2 = (const float*)d_in[7];
  const float* b2 = (const float*)d_in[8];
  float* out = (float*)d_out;

  // ws layout: wt 294912B | TA 50000*592 | TB 50000*432   (~51.5 MB total)
  uint16_t* wt = (uint16_t*)d_ws;
  uint16_t* ta = (uint16_t*)((char*)d_ws + 294912);
  uint16_t* tb = (uint16_t*)((char*)d_ws + 294912 + (size_t)N_NODES * 592);

  prep_w<<<576, 256, 0, stream>>>(W0, W1, W2, wt);
  {
    long long tot = (long long)N_NODES * 296;
    int blocks = (int)((tot + 255) / 256);
    prep_tables<<<blocks, 256, 0, stream>>>(nt, ta, tb);
  }
  edge_main<<<N_EDGES / BM, NT, 0, stream>>>(ta, tb, ei, wt, A1, b1, A2, b2, out);
}